// Round 1
// baseline (339.354 us; speedup 1.0000x reference)
//
#include <hip/hip_runtime.h>

// Problem constants (from reference):
// x: [T=63, B=1, H=16, S=384, D=128] f32
// y: [T=63, B=1, H=16, D=128, S=384] f32
// out: [63, 1, 16, 384, 384] f32 = broadcast of per-head (mean_t x) @ (mean_t y)
#define T_DIM 63
#define H_DIM 16
#define S_DIM 384
#define D_DIM 128
#define SLICE_ELEMS (H_DIM * S_DIM * D_DIM)        // 786432 floats per t-slice (x and y same size)
#define SLICE_F4    (SLICE_ELEMS / 4)              // 196608
#define OUT_TSTRIDE (H_DIM * S_DIM * S_DIM)        // 2359296 floats per t-slice of out

// Kernel 1: temporal mean over T for both x and y.
// Thread handles one float4 of one tensor; 63 strided (3 MB) coalesced loads.
__global__ __launch_bounds__(256) void treduce_kernel(
    const float* __restrict__ x, const float* __restrict__ y,
    float* __restrict__ xb, float* __restrict__ yb) {
  int tid = blockIdx.x * 256 + threadIdx.x;      // 0 .. 2*SLICE_F4-1
  const float4* src;
  float4* dst;
  if (tid < SLICE_F4) {
    src = reinterpret_cast<const float4*>(x) + tid;
    dst = reinterpret_cast<float4*>(xb) + tid;
  } else {
    tid -= SLICE_F4;
    src = reinterpret_cast<const float4*>(y) + tid;
    dst = reinterpret_cast<float4*>(yb) + tid;
  }
  float4 acc = make_float4(0.f, 0.f, 0.f, 0.f);
#pragma unroll 9
  for (int t = 0; t < T_DIM; ++t) {
    float4 v = src[(size_t)t * SLICE_F4];
    acc.x += v.x; acc.y += v.y; acc.z += v.z; acc.w += v.w;
  }
  const float s = 1.0f / (float)T_DIM;
  acc.x *= s; acc.y *= s; acc.z *= s; acc.w *= s;
  *dst = acc;
}

// Kernel 2: per-head GEMM  w[h] = xb[h] (384x128) @ yb[h] (128x384),
// fused broadcast of each 64x64 tile across all 63 timesteps of out.
// grid = (6 col-tiles, 6 row-tiles, 16 heads), block = 256 (16x16 threads, 4x4 micro-tile).
__global__ __launch_bounds__(256) void gemm_bcast_kernel(
    const float* __restrict__ xb, const float* __restrict__ yb,
    float* __restrict__ out) {
  __shared__ float As[64][132];   // 64 rows x 128 K, padded stride 132 (2-way max conflict)
  __shared__ float Bs[128][64];   // 128 K x 64 cols

  const int h  = blockIdx.z;
  const int by = blockIdx.y;   // row tile (S of A)
  const int bx = blockIdx.x;   // col tile (S of B)
  const int t  = threadIdx.x;  // 0..255

  const float* A = xb + (size_t)h * S_DIM * D_DIM;  // [384][128] row-major
  const float* B = yb + (size_t)h * D_DIM * S_DIM;  // [128][384] row-major

  // Stage A tile: rows by*64..+63, all 128 K. 2048 float4, 8 per thread.
#pragma unroll
  for (int it = 0; it < 8; ++it) {
    int l = t + it * 256;
    int row = l >> 5;        // 32 float4 per row
    int c4  = l & 31;
    float4 v = *reinterpret_cast<const float4*>(A + (size_t)(by * 64 + row) * D_DIM + c4 * 4);
    *reinterpret_cast<float4*>(&As[row][c4 * 4]) = v;  // row stride 132*4=528 B (16B-aligned)
  }
  // Stage B tile: all 128 K rows, cols bx*64..+63. 2048 float4, 8 per thread.
#pragma unroll
  for (int it = 0; it < 8; ++it) {
    int l = t + it * 256;
    int k  = l >> 4;         // 16 float4 per row
    int c4 = l & 15;
    float4 v = *reinterpret_cast<const float4*>(B + (size_t)k * S_DIM + bx * 64 + c4 * 4);
    *reinterpret_cast<float4*>(&Bs[k][c4 * 4]) = v;
  }
  __syncthreads();

  const int tx = t & 15;   // col group
  const int ty = t >> 4;   // row group
  const int r0 = ty * 4;
  const int c0 = tx * 4;

  float acc[4][4];
#pragma unroll
  for (int i = 0; i < 4; ++i)
#pragma unroll
    for (int j = 0; j < 4; ++j) acc[i][j] = 0.f;

#pragma unroll 4
  for (int k = 0; k < D_DIM; ++k) {
    float a0 = As[r0 + 0][k];
    float a1 = As[r0 + 1][k];
    float a2 = As[r0 + 2][k];
    float a3 = As[r0 + 3][k];
    float4 b = *reinterpret_cast<const float4*>(&Bs[k][c0]);
    acc[0][0] += a0 * b.x; acc[0][1] += a0 * b.y; acc[0][2] += a0 * b.z; acc[0][3] += a0 * b.w;
    acc[1][0] += a1 * b.x; acc[1][1] += a1 * b.y; acc[1][2] += a1 * b.z; acc[1][3] += a1 * b.w;
    acc[2][0] += a2 * b.x; acc[2][1] += a2 * b.y; acc[2][2] += a2 * b.z; acc[2][3] += a2 * b.w;
    acc[3][0] += a3 * b.x; acc[3][1] += a3 * b.y; acc[3][2] += a3 * b.z; acc[3][3] += a3 * b.w;
  }

  // Broadcast epilogue: write this 4x4 micro-tile into all 63 timesteps.
  float* o = out + (size_t)h * S_DIM * S_DIM + (size_t)(by * 64 + r0) * S_DIM + bx * 64 + c0;
  float4 rows[4];
#pragma unroll
  for (int i = 0; i < 4; ++i)
    rows[i] = make_float4(acc[i][0], acc[i][1], acc[i][2], acc[i][3]);

  for (int tt = 0; tt < T_DIM; ++tt) {
    float* ot = o + (size_t)tt * OUT_TSTRIDE;
#pragma unroll
    for (int i = 0; i < 4; ++i) {
      *reinterpret_cast<float4*>(ot + (size_t)i * S_DIM) = rows[i];
    }
  }
}

extern "C" void kernel_launch(void* const* d_in, const int* in_sizes, int n_in,
                              void* d_out, int out_size, void* d_ws, size_t ws_size,
                              hipStream_t stream) {
  const float* x = (const float*)d_in[0];
  const float* y = (const float*)d_in[1];
  float* out = (float*)d_out;

  float* xb = (float*)d_ws;                 // 786432 floats
  float* yb = xb + SLICE_ELEMS;             // 786432 floats (total 6 MB of ws)

  // Kernel 1: 2 * 196608 float4-threads = 393216 threads = 1536 blocks of 256
  treduce_kernel<<<dim3(2 * SLICE_F4 / 256), dim3(256), 0, stream>>>(x, y, xb, yb);

  // Kernel 2: 6x6 tiles of 64x64 per head, 16 heads
  gemm_bcast_kernel<<<dim3(6, 6, 16), dim3(256), 0, stream>>>(xb, yb, out);
}

// Round 3
// 195.205 us; speedup vs baseline: 1.7385x; 1.7385x over previous
//
#include <hip/hip_runtime.h>

// x: [T=63, B=1, H=16, S=384, D=128] f32
// y: [T=63, B=1, H=16, D=128, S=384] f32
// out: [63, 1, 16, 384, 384] f32 = broadcast of per-head (mean_t x) @ (mean_t y)
#define T_DIM 63
#define H_DIM 16
#define S_DIM 384
#define D_DIM 128
#define SLICE_ELEMS (H_DIM * S_DIM * D_DIM)        // 786432 floats per t-slice
#define SLICE_F4    (SLICE_ELEMS / 4)              // 196608
#define OUT_TSTRIDE (H_DIM * S_DIM * S_DIM)        // 2359296 floats per t-slice of out
#define T_SPLIT 7                                  // 63 = 7 groups x 9 timesteps
#define T_PER_GROUP 9

typedef float f32x4 __attribute__((ext_vector_type(4)));  // native vec for nontemporal builtin

// Kernel 1: temporal mean over T for both x and y.
__global__ __launch_bounds__(256) void treduce_kernel(
    const float* __restrict__ x, const float* __restrict__ y,
    float* __restrict__ xb, float* __restrict__ yb) {
  int tid = blockIdx.x * 256 + threadIdx.x;      // 0 .. 2*SLICE_F4-1
  const float4* src;
  float4* dst;
  if (tid < SLICE_F4) {
    src = reinterpret_cast<const float4*>(x) + tid;
    dst = reinterpret_cast<float4*>(xb) + tid;
  } else {
    tid -= SLICE_F4;
    src = reinterpret_cast<const float4*>(y) + tid;
    dst = reinterpret_cast<float4*>(yb) + tid;
  }
  float4 acc = make_float4(0.f, 0.f, 0.f, 0.f);
#pragma unroll 9
  for (int t = 0; t < T_DIM; ++t) {
    float4 v = src[(size_t)t * SLICE_F4];
    acc.x += v.x; acc.y += v.y; acc.z += v.z; acc.w += v.w;
  }
  const float s = 1.0f / (float)T_DIM;
  acc.x *= s; acc.y *= s; acc.z *= s; acc.w *= s;
  *dst = acc;
}

// Kernel 2: per-head GEMM w[h] = xb[h] (384x128) @ yb[h] (128x384), with the
// broadcast-to-63-timesteps write split across T_SPLIT blocks per tile.
// Each of the 7 blocks per (bx,by,h) recomputes the same 64x64 tile (cheap,
// A/B re-reads hit L2/L3) and writes its own 9 timesteps.
// grid = (6, 6, 16*7), block = 256 (16x16 threads, 4x4 micro-tile).
__global__ __launch_bounds__(256) void gemm_bcast_kernel(
    const float* __restrict__ xb, const float* __restrict__ yb,
    float* __restrict__ out) {
  __shared__ float As[64][132];   // padded: 2-way max bank aliasing (free)
  __shared__ float Bs[128][64];

  const int hz = blockIdx.z;
  const int h  = hz / T_SPLIT;
  const int ts = hz % T_SPLIT;     // timestep group: t in [ts*9, ts*9+9)
  const int by = blockIdx.y;
  const int bx = blockIdx.x;
  const int t  = threadIdx.x;

  const float* A = xb + (size_t)h * S_DIM * D_DIM;  // [384][128] row-major
  const float* B = yb + (size_t)h * D_DIM * S_DIM;  // [128][384] row-major

#pragma unroll
  for (int it = 0; it < 8; ++it) {
    int l = t + it * 256;
    int row = l >> 5;        // 32 float4 per row
    int c4  = l & 31;
    float4 v = *reinterpret_cast<const float4*>(A + (size_t)(by * 64 + row) * D_DIM + c4 * 4);
    *reinterpret_cast<float4*>(&As[row][c4 * 4]) = v;
  }
#pragma unroll
  for (int it = 0; it < 8; ++it) {
    int l = t + it * 256;
    int k  = l >> 4;         // 16 float4 per row
    int c4 = l & 15;
    float4 v = *reinterpret_cast<const float4*>(B + (size_t)k * S_DIM + bx * 64 + c4 * 4);
    *reinterpret_cast<float4*>(&Bs[k][c4 * 4]) = v;
  }
  __syncthreads();

  const int tx = t & 15;
  const int ty = t >> 4;
  const int r0 = ty * 4;
  const int c0 = tx * 4;

  float acc[4][4];
#pragma unroll
  for (int i = 0; i < 4; ++i)
#pragma unroll
    for (int j = 0; j < 4; ++j) acc[i][j] = 0.f;

#pragma unroll 4
  for (int k = 0; k < D_DIM; ++k) {
    float a0 = As[r0 + 0][k];
    float a1 = As[r0 + 1][k];
    float a2 = As[r0 + 2][k];
    float a3 = As[r0 + 3][k];
    float4 b = *reinterpret_cast<const float4*>(&Bs[k][c0]);
    acc[0][0] += a0 * b.x; acc[0][1] += a0 * b.y; acc[0][2] += a0 * b.z; acc[0][3] += a0 * b.w;
    acc[1][0] += a1 * b.x; acc[1][1] += a1 * b.y; acc[1][2] += a1 * b.z; acc[1][3] += a1 * b.w;
    acc[2][0] += a2 * b.x; acc[2][1] += a2 * b.y; acc[2][2] += a2 * b.z; acc[2][3] += a2 * b.w;
    acc[3][0] += a3 * b.x; acc[3][1] += a3 * b.y; acc[3][2] += a3 * b.z; acc[3][3] += a3 * b.w;
  }

  f32x4 rows[4];
#pragma unroll
  for (int i = 0; i < 4; ++i) {
    f32x4 r; r.x = acc[i][0]; r.y = acc[i][1]; r.z = acc[i][2]; r.w = acc[i][3];
    rows[i] = r;
  }

  // Write this tile into timesteps [ts*9, ts*9+9). Nontemporal: out is
  // write-once and never re-read; keep L2 for the A/B staging re-reads.
  float* o = out + (size_t)h * S_DIM * S_DIM + (size_t)(by * 64 + r0) * S_DIM + bx * 64 + c0;
#pragma unroll
  for (int q = 0; q < T_PER_GROUP; ++q) {
    int tt = ts * T_PER_GROUP + q;
    float* ot = o + (size_t)tt * OUT_TSTRIDE;
#pragma unroll
    for (int i = 0; i < 4; ++i) {
      __builtin_nontemporal_store(rows[i], reinterpret_cast<f32x4*>(ot + (size_t)i * S_DIM));
    }
  }
}

extern "C" void kernel_launch(void* const* d_in, const int* in_sizes, int n_in,
                              void* d_out, int out_size, void* d_ws, size_t ws_size,
                              hipStream_t stream) {
  const float* x = (const float*)d_in[0];
  const float* y = (const float*)d_in[1];
  float* out = (float*)d_out;

  float* xb = (float*)d_ws;                 // 786432 floats
  float* yb = xb + SLICE_ELEMS;             // 786432 floats

  treduce_kernel<<<dim3(2 * SLICE_F4 / 256), dim3(256), 0, stream>>>(x, y, xb, yb);
  gemm_bcast_kernel<<<dim3(6, 6, H_DIM * T_SPLIT), dim3(256), 0, stream>>>(xb, yb, out);
}

// Round 4
// 188.146 us; speedup vs baseline: 1.8037x; 1.0375x over previous
//
#include <hip/hip_runtime.h>

// x: [T=63, B=1, H=16, S=384, D=128] f32
// y: [T=63, B=1, H=16, D=128, S=384] f32
// out: [63, 1, 16, 384, 384] f32 = broadcast of per-head (mean_t x) @ (mean_t y)
#define T_DIM 63
#define H_DIM 16
#define S_DIM 384
#define D_DIM 128
#define SLICE_ELEMS (H_DIM * S_DIM * D_DIM)        // 786432 floats per t-slice
#define SLICE_F4    (SLICE_ELEMS / 4)              // 196608
#define OUT_TSTRIDE (H_DIM * S_DIM * S_DIM)        // 2359296 floats per t-slice of out
#define W_F4        (OUT_TSTRIDE / 4)              // 589824 float4 per t-slice

typedef float f32x4 __attribute__((ext_vector_type(4)));

// Kernel 1: temporal mean over T for both x and y. Pure read-bound (396 MB).
// Nontemporal loads: x/y are never touched again — don't pollute L2.
__global__ __launch_bounds__(256) void treduce_kernel(
    const float* __restrict__ x, const float* __restrict__ y,
    float* __restrict__ xb, float* __restrict__ yb) {
  int tid = blockIdx.x * 256 + threadIdx.x;      // 0 .. 2*SLICE_F4-1
  const f32x4* src;
  f32x4* dst;
  if (tid < SLICE_F4) {
    src = reinterpret_cast<const f32x4*>(x) + tid;
    dst = reinterpret_cast<f32x4*>(xb) + tid;
  } else {
    tid -= SLICE_F4;
    src = reinterpret_cast<const f32x4*>(y) + tid;
    dst = reinterpret_cast<f32x4*>(yb) + tid;
  }
  f32x4 acc = (f32x4)0.f;
#pragma unroll 9
  for (int t = 0; t < T_DIM; ++t) {
    f32x4 v = __builtin_nontemporal_load(src + (size_t)t * SLICE_F4);
    acc += v;
  }
  acc *= (1.0f / (float)T_DIM);
  *dst = acc;
}

// Kernel 2: per-head GEMM w[h] = xb[h] (384x128) @ yb[h] (128x384), computed
// ONCE, written straight into out's t=0 slice (w[h,s1,s2] == out[0,0,h,s1,s2]).
// grid = (6, 6, 16), block = 256 (16x16 threads, 4x4 micro-tile). ~0.6 GFLOP.
__global__ __launch_bounds__(256) void gemm_kernel(
    const float* __restrict__ xb, const float* __restrict__ yb,
    float* __restrict__ out) {
  __shared__ float As[64][132];   // padded: 2-way max bank aliasing (free)
  __shared__ float Bs[128][64];

  const int h  = blockIdx.z;
  const int by = blockIdx.y;
  const int bx = blockIdx.x;
  const int t  = threadIdx.x;

  const float* A = xb + (size_t)h * S_DIM * D_DIM;  // [384][128] row-major
  const float* B = yb + (size_t)h * D_DIM * S_DIM;  // [128][384] row-major

#pragma unroll
  for (int it = 0; it < 8; ++it) {
    int l = t + it * 256;
    int row = l >> 5;        // 32 float4 per row
    int c4  = l & 31;
    float4 v = *reinterpret_cast<const float4*>(A + (size_t)(by * 64 + row) * D_DIM + c4 * 4);
    *reinterpret_cast<float4*>(&As[row][c4 * 4]) = v;
  }
#pragma unroll
  for (int it = 0; it < 8; ++it) {
    int l = t + it * 256;
    int k  = l >> 4;         // 16 float4 per row
    int c4 = l & 15;
    float4 v = *reinterpret_cast<const float4*>(B + (size_t)k * S_DIM + bx * 64 + c4 * 4);
    *reinterpret_cast<float4*>(&Bs[k][c4 * 4]) = v;
  }
  __syncthreads();

  const int tx = t & 15;
  const int ty = t >> 4;
  const int r0 = ty * 4;
  const int c0 = tx * 4;

  float acc[4][4];
#pragma unroll
  for (int i = 0; i < 4; ++i)
#pragma unroll
    for (int j = 0; j < 4; ++j) acc[i][j] = 0.f;

#pragma unroll 4
  for (int k = 0; k < D_DIM; ++k) {
    float a0 = As[r0 + 0][k];
    float a1 = As[r0 + 1][k];
    float a2 = As[r0 + 2][k];
    float a3 = As[r0 + 3][k];
    float4 b = *reinterpret_cast<const float4*>(&Bs[k][c0]);
    acc[0][0] += a0 * b.x; acc[0][1] += a0 * b.y; acc[0][2] += a0 * b.z; acc[0][3] += a0 * b.w;
    acc[1][0] += a1 * b.x; acc[1][1] += a1 * b.y; acc[1][2] += a1 * b.z; acc[1][3] += a1 * b.w;
    acc[2][0] += a2 * b.x; acc[2][1] += a2 * b.y; acc[2][2] += a2 * b.z; acc[2][3] += a2 * b.w;
    acc[3][0] += a3 * b.x; acc[3][1] += a3 * b.y; acc[3][2] += a3 * b.z; acc[3][3] += a3 * b.w;
  }

  // Write the tile ONCE into the t=0 slice (regular stores: k3 re-reads them).
  float* o = out + (size_t)h * S_DIM * S_DIM + (size_t)(by * 64 + r0) * S_DIM + bx * 64 + c0;
#pragma unroll
  for (int i = 0; i < 4; ++i) {
    *reinterpret_cast<float4*>(o + (size_t)i * S_DIM) =
        make_float4(acc[i][0], acc[i][1], acc[i][2], acc[i][3]);
  }
}

// Kernel 3: pure broadcast. Thread i reads float4 i of the t=0 slice (hot in
// L2/L3, only 9.4 MB) and nontemporal-stores it to t=1..62 (584 MB of writes).
__global__ __launch_bounds__(256) void bcast_kernel(float* __restrict__ out) {
  int i = blockIdx.x * 256 + threadIdx.x;   // 0 .. W_F4-1
  f32x4* o4 = reinterpret_cast<f32x4*>(out);
  f32x4 v = o4[i];
#pragma unroll 31
  for (int t = 1; t < T_DIM; ++t) {
    __builtin_nontemporal_store(v, o4 + (size_t)t * W_F4 + i);
  }
}

extern "C" void kernel_launch(void* const* d_in, const int* in_sizes, int n_in,
                              void* d_out, int out_size, void* d_ws, size_t ws_size,
                              hipStream_t stream) {
  const float* x = (const float*)d_in[0];
  const float* y = (const float*)d_in[1];
  float* out = (float*)d_out;

  float* xb = (float*)d_ws;                 // 786432 floats
  float* yb = xb + SLICE_ELEMS;             // 786432 floats (6 MB total)

  treduce_kernel<<<dim3(2 * SLICE_F4 / 256), dim3(256), 0, stream>>>(x, y, xb, yb);
  gemm_kernel<<<dim3(6, 6, H_DIM), dim3(256), 0, stream>>>(xb, yb, out);
  bcast_kernel<<<dim3(W_F4 / 256), dim3(256), 0, stream>>>(out);
}